// Round 1
// 1370.482 us; speedup vs baseline: 1.6613x; 1.6613x over previous
//
#include <hip/hip_runtime.h>
#include <hip/hip_bf16.h>

typedef __bf16 bf16x8 __attribute__((ext_vector_type(8)));
typedef float f32x4 __attribute__((ext_vector_type(4)));

static constexpr int BATCH  = 8192;
static constexpr int EMBED  = 1024;
static constexpr int HIDDEN = 2048;
static constexpr int KD     = EMBED + HIDDEN;  // 3072

__device__ __forceinline__ float sigm(float x) { return 1.0f / (1.0f + __expf(-x)); }
__device__ __forceinline__ float tanh_fast(float x) { return 2.0f / (1.0f + __expf(-2.0f * x)) - 1.0f; }

__device__ __forceinline__ unsigned pack2(float a, float b) {
  __bf16 ha = (__bf16)a, hb = (__bf16)b;
  return (unsigned)__builtin_bit_cast(unsigned short, ha) |
         ((unsigned)__builtin_bit_cast(unsigned short, hb) << 16);
}
__device__ __forceinline__ float unp2(unsigned u, int hi) {
  return __builtin_bit_cast(float, hi ? (u & 0xffff0000u) : (u << 16));
}

// load 8 f32 -> bf16x8 (used by one-time convert kernels only)
__device__ __forceinline__ bf16x8 loadcvt8(const float* __restrict__ p) {
  f32x4 lo = *(const f32x4*)p;
  f32x4 hi = *(const f32x4*)(p + 4);
  bf16x8 r;
  r[0] = (__bf16)lo[0]; r[1] = (__bf16)lo[1]; r[2] = (__bf16)lo[2]; r[3] = (__bf16)lo[3];
  r[4] = (__bf16)hi[0]; r[5] = (__bf16)hi[1]; r[6] = (__bf16)hi[2]; r[7] = (__bf16)hi[3];
  return r;
}

// async global->LDS, 16B per lane. LDS dest = wave-uniform base + lane*16.
__device__ __forceinline__ void glds16(const void* g, void* l) {
  __builtin_amdgcn_global_load_lds((const __attribute__((address_space(1))) void*)g,
                                   (__attribute__((address_space(3))) void*)l, 16, 0, 0);
}

// ---------------- one-time converts (f32 -> bf16) ----------------
// A = concat(x, short_term) : [BATCH, KD]
__global__ __launch_bounds__(256) void cvtA_kernel(const float* __restrict__ x,
                                                   const float* __restrict__ st,
                                                   __bf16* __restrict__ dst) {
  const long i8 = ((long)blockIdx.x * 256 + threadIdx.x) * 8;
  const int r = (int)(i8 / KD);
  const int c = (int)(i8 - (long)r * KD);
  const float* s = (c < EMBED) ? (x + (long)r * EMBED + c)
                               : (st + (long)r * HIDDEN + (c - EMBED));
  *(bf16x8*)(dst + i8) = loadcvt8(s);
}

// W4 = [4][HIDDEN][KD] (f,i,c,o)
__global__ __launch_bounds__(256) void cvtW_kernel(const float* __restrict__ Wf,
                                                   const float* __restrict__ Wi,
                                                   const float* __restrict__ Wc,
                                                   const float* __restrict__ Wo,
                                                   __bf16* __restrict__ dst) {
  const int g = blockIdx.y;
  const float* s = (g == 0) ? Wf : (g == 1) ? Wi : (g == 2) ? Wc : Wo;
  const long off = ((long)blockIdx.x * 256 + threadIdx.x) * 8;
  *(bf16x8*)(dst + (long)g * HIDDEN * KD + off) = loadcvt8(s + off);
}

// contiguous convert (W_h2o)
__global__ __launch_bounds__(256) void cvtC_kernel(const float* __restrict__ s,
                                                   __bf16* __restrict__ d) {
  const long off = ((long)blockIdx.x * 256 + threadIdx.x) * 8;
  *(bf16x8*)(d + off) = loadcvt8(s + off);
}

// ---------------- Kernel 1: fused 4-gate GEMM + LSTM cell update ----------------
// grid = (HIDDEN/128, BATCH/128), block = 256 (4 waves, 2x2 of 64x64 wave tiles)
__global__ __launch_bounds__(256) void lstm_gates_kernel(
    const __bf16* __restrict__ A,   // [BATCH, KD] bf16
    const __bf16* __restrict__ W4,  // [4, HIDDEN, KD] bf16
    const float* __restrict__ lt,
    const float* __restrict__ bfp, const float* __restrict__ bip,
    const float* __restrict__ bcp, const float* __restrict__ bop,
    float* __restrict__ out1 /* o stash -> final output buffer */,
    float* __restrict__ out2 /* C_new, f32 */,
    __bf16* __restrict__ cnb /* C_new, bf16 for kernel 2 */)
{
  __shared__ __align__(16) __bf16 sA[128 * 32];
  __shared__ __align__(16) __bf16 sB[128 * 32];

  const int tid  = threadIdx.x;
  const int lane = tid & 63;
  const int wave = tid >> 6;
  const int waveM = wave >> 1;
  const int waveN = wave & 1;

  const int row0 = blockIdx.y * 128;  // batch tile
  const int n0   = blockIdx.x * 128;  // hidden tile

  // staging: seg = wave*2+j covers tile rows seg*16..seg*16+15 (1KB per wave-issue)
  const int sRow = lane >> 2;        // 0..15
  const int sCol = (lane & 3) * 8;   // element offset within 32-wide K chunk
  const long aA0 = (long)(row0 + wave * 32 +      sRow) * KD + sCol;
  const long aA1 = (long)(row0 + wave * 32 + 16 + sRow) * KD + sCol;
  const long aB0 = (long)(n0   + wave * 32 +      sRow) * KD + sCol;
  const long aB1 = (long)(n0   + wave * 32 + 16 + sRow) * KD + sCol;
  __bf16* lA0 = sA + wave * 1024;        // (wave*2)*512 elems
  __bf16* lA1 = sA + wave * 1024 + 512;
  __bf16* lB0 = sB + wave * 1024;
  __bf16* lB1 = sB + wave * 1024 + 512;

  // fragment reads; A[m][k]: m=lane&15, k=(lane>>4)*8+j (m92/m97 verified)
  const int kr = (lane >> 4) * 8;
  const int rA = (waveM * 64 + (lane & 15)) * 32 + kr;
  const int rB = (waveN * 64 + (lane & 15)) * 32 + kr;

  f32x4 acc[4][4];

  auto kloop = [&](const __bf16* __restrict__ Wg) {
#pragma unroll
    for (int fm = 0; fm < 4; ++fm)
#pragma unroll
      for (int fn = 0; fn < 4; ++fn)
        acc[fm][fn] = (f32x4){0.f, 0.f, 0.f, 0.f};

    for (int k0 = 0; k0 < KD; k0 += 32) {
      __syncthreads();  // prior ds_reads done before overwrite
      glds16(A  + aA0 + k0, lA0);
      glds16(A  + aA1 + k0, lA1);
      glds16(Wg + aB0 + k0, lB0);
      glds16(Wg + aB1 + k0, lB1);
      __syncthreads();  // compiler drains vmcnt(0) before barrier -> staging visible

      bf16x8 a[4], b[4];
#pragma unroll
      for (int f = 0; f < 4; ++f) {
        a[f] = *(const bf16x8*)(sA + rA + f * 16 * 32);
        b[f] = *(const bf16x8*)(sB + rB + f * 16 * 32);
      }
#pragma unroll
      for (int fm = 0; fm < 4; ++fm)
#pragma unroll
        for (int fn = 0; fn < 4; ++fn)
          acc[fm][fn] = __builtin_amdgcn_mfma_f32_16x16x32_bf16(a[fm], b[fn], acc[fm][fn], 0, 0, 0);
    }
  };

  // C/D layout (m89/m91 verified): col = lane&15, row = (lane>>4)*4 + reg
  const int colB = n0 + waveN * 64 + (lane & 15);
  const int rowB = row0 + waveM * 64 + ((lane >> 4) << 2);

  unsigned cn_pk[4][4][2];  // f*long_term, bf16-packed
  unsigned i_pk[4][4][2];   // i gate, bf16-packed

  // ---- gate f: stash f*long_term ----
  kloop(W4);
#pragma unroll
  for (int fn = 0; fn < 4; ++fn) {
    const int col = colB + fn * 16;
    const float bv = bfp[col];
#pragma unroll
    for (int fm = 0; fm < 4; ++fm) {
      float c_[4];
#pragma unroll
      for (int rr = 0; rr < 4; ++rr) {
        const int row = rowB + fm * 16 + rr;
        const float fg = sigm(acc[fm][fn][rr] + bv);
        c_[rr] = fg * lt[(size_t)row * HIDDEN + col];
      }
      cn_pk[fm][fn][0] = pack2(c_[0], c_[1]);
      cn_pk[fm][fn][1] = pack2(c_[2], c_[3]);
    }
  }

  // ---- gate i: stash sigmoid ----
  kloop(W4 + (long)HIDDEN * KD);
#pragma unroll
  for (int fn = 0; fn < 4; ++fn) {
    const int col = colB + fn * 16;
    const float bv = bip[col];
#pragma unroll
    for (int fm = 0; fm < 4; ++fm) {
      float c_[4];
#pragma unroll
      for (int rr = 0; rr < 4; ++rr)
        c_[rr] = sigm(acc[fm][fn][rr] + bv);
      i_pk[fm][fn][0] = pack2(c_[0], c_[1]);
      i_pk[fm][fn][1] = pack2(c_[2], c_[3]);
    }
  }

  // ---- gate c: C_new = f*lt + i*tanh(c~)  -> out2 (f32) + cnb (bf16) ----
  kloop(W4 + 2 * (long)HIDDEN * KD);
#pragma unroll
  for (int fn = 0; fn < 4; ++fn) {
    const int col = colB + fn * 16;
    const float bv = bcp[col];
#pragma unroll
    for (int fm = 0; fm < 4; ++fm) {
#pragma unroll
      for (int rr = 0; rr < 4; ++rr) {
        const int row = rowB + fm * 16 + rr;
        const float ct = tanh_fast(acc[fm][fn][rr] + bv);
        const float cn = unp2(cn_pk[fm][fn][rr >> 1], rr & 1)
                       + unp2(i_pk[fm][fn][rr >> 1], rr & 1) * ct;
        const size_t idx = (size_t)row * HIDDEN + col;
        out2[idx] = cn;
        cnb[idx] = (__bf16)cn;
      }
    }
  }

  // ---- gate o: stash sigmoid into out1 (f32; overwritten by kernel 2) ----
  kloop(W4 + 3 * (long)HIDDEN * KD);
#pragma unroll
  for (int fn = 0; fn < 4; ++fn) {
    const int col = colB + fn * 16;
    const float bv = bop[col];
#pragma unroll
    for (int fm = 0; fm < 4; ++fm) {
#pragma unroll
      for (int rr = 0; rr < 4; ++rr) {
        const int row = rowB + fm * 16 + rr;
        out1[(size_t)row * HIDDEN + col] = sigm(acc[fm][fn][rr] + bv);
      }
    }
  }
}

// ---------------- Kernel 2: output = tanh(C_new @ W_h2o^T + b) * o ----------------
__global__ __launch_bounds__(256) void lstm_out_kernel(
    const __bf16* __restrict__ cnb, const __bf16* __restrict__ Whb,
    const float* __restrict__ bh, float* __restrict__ out1)
{
  __shared__ __align__(16) __bf16 sA[128 * 32];
  __shared__ __align__(16) __bf16 sB[128 * 32];

  const int tid  = threadIdx.x;
  const int lane = tid & 63;
  const int wave = tid >> 6;
  const int waveM = wave >> 1;
  const int waveN = wave & 1;

  const int row0 = blockIdx.y * 128;
  const int n0   = blockIdx.x * 128;

  const int sRow = lane >> 2;
  const int sCol = (lane & 3) * 8;
  const long aA0 = (long)(row0 + wave * 32 +      sRow) * HIDDEN + sCol;
  const long aA1 = (long)(row0 + wave * 32 + 16 + sRow) * HIDDEN + sCol;
  const long aB0 = (long)(n0   + wave * 32 +      sRow) * HIDDEN + sCol;
  const long aB1 = (long)(n0   + wave * 32 + 16 + sRow) * HIDDEN + sCol;
  __bf16* lA0 = sA + wave * 1024;
  __bf16* lA1 = sA + wave * 1024 + 512;
  __bf16* lB0 = sB + wave * 1024;
  __bf16* lB1 = sB + wave * 1024 + 512;

  const int kr = (lane >> 4) * 8;
  const int rA = (waveM * 64 + (lane & 15)) * 32 + kr;
  const int rB = (waveN * 64 + (lane & 15)) * 32 + kr;

  f32x4 acc[4][4];
#pragma unroll
  for (int fm = 0; fm < 4; ++fm)
#pragma unroll
    for (int fn = 0; fn < 4; ++fn)
      acc[fm][fn] = (f32x4){0.f, 0.f, 0.f, 0.f};

  for (int k0 = 0; k0 < HIDDEN; k0 += 32) {
    __syncthreads();
    glds16(cnb + aA0 + k0, lA0);
    glds16(cnb + aA1 + k0, lA1);
    glds16(Whb + aB0 + k0, lB0);
    glds16(Whb + aB1 + k0, lB1);
    __syncthreads();

    bf16x8 a[4], b[4];
#pragma unroll
    for (int f = 0; f < 4; ++f) {
      a[f] = *(const bf16x8*)(sA + rA + f * 16 * 32);
      b[f] = *(const bf16x8*)(sB + rB + f * 16 * 32);
    }
#pragma unroll
    for (int fm = 0; fm < 4; ++fm)
#pragma unroll
      for (int fn = 0; fn < 4; ++fn)
        acc[fm][fn] = __builtin_amdgcn_mfma_f32_16x16x32_bf16(a[fm], b[fn], acc[fm][fn], 0, 0, 0);
  }

  const int colB = n0 + waveN * 64 + (lane & 15);
  const int rowB = row0 + waveM * 64 + ((lane >> 4) << 2);
#pragma unroll
  for (int fn = 0; fn < 4; ++fn) {
    const int col = colB + fn * 16;
    const float bv = bh[col];
#pragma unroll
    for (int fm = 0; fm < 4; ++fm) {
#pragma unroll
      for (int rr = 0; rr < 4; ++rr) {
        const int row = rowB + fm * 16 + rr;
        const size_t idx = (size_t)row * HIDDEN + col;
        const float v = tanh_fast(acc[fm][fn][rr] + bv);
        const float ov = out1[idx];  // o gate stashed by kernel 1
        out1[idx] = v * ov;
      }
    }
  }
}

extern "C" void kernel_launch(void* const* d_in, const int* in_sizes, int n_in,
                              void* d_out, int out_size, void* d_ws, size_t ws_size,
                              hipStream_t stream) {
  const float* x   = (const float*)d_in[0];
  const float* st  = (const float*)d_in[1];
  const float* lt  = (const float*)d_in[2];
  const float* Wf  = (const float*)d_in[3];
  const float* bfp = (const float*)d_in[4];
  const float* Wi  = (const float*)d_in[5];
  const float* bip = (const float*)d_in[6];
  const float* Wc  = (const float*)d_in[7];
  const float* bcp = (const float*)d_in[8];
  const float* Wo  = (const float*)d_in[9];
  const float* bop = (const float*)d_in[10];
  const float* Wh  = (const float*)d_in[11];
  const float* bh  = (const float*)d_in[12];

  float* out1 = (float*)d_out;                        // output [B,H] f32
  float* out2 = out1 + (size_t)BATCH * HIDDEN;        // C_new [B,H] f32

  // workspace partition (bf16): A | W4 | Wh | C_new  = ~143 MB
  __bf16* Ab  = (__bf16*)d_ws;                        // [BATCH, KD]
  __bf16* W4b = Ab + (size_t)BATCH * KD;              // [4, HIDDEN, KD]
  __bf16* Whb = W4b + (size_t)4 * HIDDEN * KD;        // [HIDDEN, HIDDEN]
  __bf16* Cnb = Whb + (size_t)HIDDEN * HIDDEN;        // [BATCH, HIDDEN]

  cvtA_kernel<<<dim3((BATCH * (long)KD) / 2048), 256, 0, stream>>>(x, st, Ab);
  cvtW_kernel<<<dim3((HIDDEN * (long)KD) / 2048, 4), 256, 0, stream>>>(Wf, Wi, Wc, Wo, W4b);
  cvtC_kernel<<<dim3((HIDDEN * (long)HIDDEN) / 2048), 256, 0, stream>>>(Wh, Whb);

  dim3 grid(HIDDEN / 128, BATCH / 128);  // (16, 64)
  lstm_gates_kernel<<<grid, 256, 0, stream>>>(Ab, W4b, lt, bfp, bip, bcp, bop, out1, out2, Cnb);
  lstm_out_kernel<<<grid, 256, 0, stream>>>(Cnb, Whb, bh, out1);
}

// Round 2
// 1051.134 us; speedup vs baseline: 2.1661x; 1.3038x over previous
//
#include <hip/hip_runtime.h>
#include <hip/hip_bf16.h>

typedef __bf16 bf16x8 __attribute__((ext_vector_type(8)));
typedef float f32x4 __attribute__((ext_vector_type(4)));

static constexpr int BATCH  = 8192;
static constexpr int EMBED  = 1024;
static constexpr int HIDDEN = 2048;
static constexpr int KD     = EMBED + HIDDEN;  // 3072

__device__ __forceinline__ float sigm(float x) { return 1.0f / (1.0f + __expf(-x)); }
__device__ __forceinline__ float tanh_fast(float x) { return 2.0f / (1.0f + __expf(-2.0f * x)) - 1.0f; }

// load 8 f32 -> bf16x8 (one-time convert kernels)
__device__ __forceinline__ bf16x8 loadcvt8(const float* __restrict__ p) {
  f32x4 lo = *(const f32x4*)p;
  f32x4 hi = *(const f32x4*)(p + 4);
  bf16x8 r;
  r[0] = (__bf16)lo[0]; r[1] = (__bf16)lo[1]; r[2] = (__bf16)lo[2]; r[3] = (__bf16)lo[3];
  r[4] = (__bf16)hi[0]; r[5] = (__bf16)hi[1]; r[6] = (__bf16)hi[2]; r[7] = (__bf16)hi[3];
  return r;
}

// async global->LDS, 16B per lane. LDS dest = wave-uniform base + lane*16.
__device__ __forceinline__ void glds16(const void* g, void* l) {
  __builtin_amdgcn_global_load_lds((const __attribute__((address_space(1))) void*)g,
                                   (__attribute__((address_space(3))) void*)l, 16, 0, 0);
}

// ---------------- one-time converts (f32 -> bf16) ----------------
__global__ __launch_bounds__(256) void cvtA_kernel(const float* __restrict__ x,
                                                   const float* __restrict__ st,
                                                   __bf16* __restrict__ dst) {
  const long i8 = ((long)blockIdx.x * 256 + threadIdx.x) * 8;
  const int r = (int)(i8 / KD);
  const int c = (int)(i8 - (long)r * KD);
  const float* s = (c < EMBED) ? (x + (long)r * EMBED + c)
                               : (st + (long)r * HIDDEN + (c - EMBED));
  *(bf16x8*)(dst + i8) = loadcvt8(s);
}

__global__ __launch_bounds__(256) void cvtW_kernel(const float* __restrict__ Wf,
                                                   const float* __restrict__ Wi,
                                                   const float* __restrict__ Wc,
                                                   const float* __restrict__ Wo,
                                                   __bf16* __restrict__ dst) {
  const int g = blockIdx.y;
  const float* s = (g == 0) ? Wf : (g == 1) ? Wi : (g == 2) ? Wc : Wo;
  const long off = ((long)blockIdx.x * 256 + threadIdx.x) * 8;
  *(bf16x8*)(dst + (long)g * HIDDEN * KD + off) = loadcvt8(s + off);
}

__global__ __launch_bounds__(256) void cvtC_kernel(const float* __restrict__ s,
                                                   __bf16* __restrict__ d) {
  const long off = ((long)blockIdx.x * 256 + threadIdx.x) * 8;
  *(bf16x8*)(d + off) = loadcvt8(s + off);
}

// ---------------- Kernel 1: per-gate GEMM (gate = blockIdx.z) ----------------
// grid = (HIDDEN/128, BATCH/128, 4), block = 256 (4 waves, 2x2 of 64x64 wave tiles)
// g=0: flt = sigm(f)*lt (bf16)   g=1: ig = sigm(i) (bf16)
// g=2: out2 = tanh(c) (f32 temp) g=3: out1 = sigm(o) (f32 temp)
__global__ __launch_bounds__(256, 3) void lstm_gates_kernel(
    const __bf16* __restrict__ A,   // [BATCH, KD] bf16
    const __bf16* __restrict__ W4,  // [4, HIDDEN, KD] bf16
    const float* __restrict__ lt,
    const float* __restrict__ bfp, const float* __restrict__ bip,
    const float* __restrict__ bcp, const float* __restrict__ bop,
    float* __restrict__ out1, float* __restrict__ out2,
    __bf16* __restrict__ flt, __bf16* __restrict__ ig)
{
  __shared__ __align__(16) __bf16 sA[128 * 32];
  __shared__ __align__(16) __bf16 sB[128 * 32];

  const int tid  = threadIdx.x;
  const int lane = tid & 63;
  const int wave = tid >> 6;
  const int waveM = wave >> 1;
  const int waveN = wave & 1;
  const int gate = blockIdx.z;

  const int row0 = blockIdx.y * 128;  // batch tile
  const int n0   = blockIdx.x * 128;  // hidden tile

  const __bf16* __restrict__ Wg = W4 + (long)gate * HIDDEN * KD;

  // staging: seg = wave*2+j covers tile rows seg*16..seg*16+15 (1KB per wave-issue)
  const int sRow = lane >> 2;        // 0..15
  const int sCol = (lane & 3) * 8;
  const long aA0 = (long)(row0 + wave * 32 +      sRow) * KD + sCol;
  const long aA1 = (long)(row0 + wave * 32 + 16 + sRow) * KD + sCol;
  const long aB0 = (long)(n0   + wave * 32 +      sRow) * KD + sCol;
  const long aB1 = (long)(n0   + wave * 32 + 16 + sRow) * KD + sCol;
  __bf16* lA0 = sA + wave * 1024;
  __bf16* lA1 = sA + wave * 1024 + 512;
  __bf16* lB0 = sB + wave * 1024;
  __bf16* lB1 = sB + wave * 1024 + 512;

  // fragment reads; A[m][k]: m=lane&15, k=(lane>>4)*8+j (m92/m97 verified)
  const int kr = (lane >> 4) * 8;
  const int rA = (waveM * 64 + (lane & 15)) * 32 + kr;
  const int rB = (waveN * 64 + (lane & 15)) * 32 + kr;

  f32x4 acc[4][4];
#pragma unroll
  for (int fm = 0; fm < 4; ++fm)
#pragma unroll
    for (int fn = 0; fn < 4; ++fn)
      acc[fm][fn] = (f32x4){0.f, 0.f, 0.f, 0.f};

  for (int k0 = 0; k0 < KD; k0 += 32) {
    __syncthreads();  // prior ds_reads done before overwrite
    glds16(A  + aA0 + k0, lA0);
    glds16(A  + aA1 + k0, lA1);
    glds16(Wg + aB0 + k0, lB0);
    glds16(Wg + aB1 + k0, lB1);
    __syncthreads();  // vmcnt(0) drained before barrier -> staging visible

    bf16x8 a[4], b[4];
#pragma unroll
    for (int f = 0; f < 4; ++f) {
      a[f] = *(const bf16x8*)(sA + rA + f * 16 * 32);
      b[f] = *(const bf16x8*)(sB + rB + f * 16 * 32);
    }
#pragma unroll
    for (int fm = 0; fm < 4; ++fm)
#pragma unroll
      for (int fn = 0; fn < 4; ++fn)
        acc[fm][fn] = __builtin_amdgcn_mfma_f32_16x16x32_bf16(a[fm], b[fn], acc[fm][fn], 0, 0, 0);
  }

  // C/D layout (m89/m91 verified): col = lane&15, row = (lane>>4)*4 + reg
  const int colB = n0 + waveN * 64 + (lane & 15);
  const int rowB = row0 + waveM * 64 + ((lane >> 4) << 2);

  const float* bias = (gate == 0) ? bfp : (gate == 1) ? bip : (gate == 2) ? bcp : bop;

#pragma unroll
  for (int fn = 0; fn < 4; ++fn) {
    const int col = colB + fn * 16;
    const float bv = bias[col];
#pragma unroll
    for (int fm = 0; fm < 4; ++fm) {
#pragma unroll
      for (int rr = 0; rr < 4; ++rr) {
        const int row = rowB + fm * 16 + rr;
        const size_t idx = (size_t)row * HIDDEN + col;
        const float v = acc[fm][fn][rr] + bv;
        if (gate == 0) {
          flt[idx] = (__bf16)(sigm(v) * lt[idx]);
        } else if (gate == 1) {
          ig[idx] = (__bf16)sigm(v);
        } else if (gate == 2) {
          out2[idx] = tanh_fast(v);
        } else {
          out1[idx] = sigm(v);
        }
      }
    }
  }
}

// ---------------- elementwise: C_new = flt + ig*tc ----------------
__global__ __launch_bounds__(256) void lstm_cell_kernel(
    const __bf16* __restrict__ flt, const __bf16* __restrict__ ig,
    float* __restrict__ out2 /* in: tanh(c), out: C_new */,
    __bf16* __restrict__ cnb)
{
  const long i8 = ((long)blockIdx.x * 256 + threadIdx.x) * 8;
  bf16x8 f8 = *(const bf16x8*)(flt + i8);
  bf16x8 i8v = *(const bf16x8*)(ig + i8);
  f32x4 t0 = *(const f32x4*)(out2 + i8);
  f32x4 t1 = *(const f32x4*)(out2 + i8 + 4);
  f32x4 c0, c1;
  bf16x8 cb;
#pragma unroll
  for (int j = 0; j < 4; ++j) {
    c0[j] = (float)f8[j] + (float)i8v[j] * t0[j];
    c1[j] = (float)f8[j + 4] + (float)i8v[j + 4] * t1[j];
    cb[j] = (__bf16)c0[j];
    cb[j + 4] = (__bf16)c1[j];
  }
  *(f32x4*)(out2 + i8) = c0;
  *(f32x4*)(out2 + i8 + 4) = c1;
  *(bf16x8*)(cnb + i8) = cb;
}

// ---------------- Kernel 2: output = tanh(C_new @ W_h2o^T + b) * o ----------------
__global__ __launch_bounds__(256, 3) void lstm_out_kernel(
    const __bf16* __restrict__ cnb, const __bf16* __restrict__ Whb,
    const float* __restrict__ bh, float* __restrict__ out1)
{
  __shared__ __align__(16) __bf16 sA[128 * 32];
  __shared__ __align__(16) __bf16 sB[128 * 32];

  const int tid  = threadIdx.x;
  const int lane = tid & 63;
  const int wave = tid >> 6;
  const int waveM = wave >> 1;
  const int waveN = wave & 1;

  const int row0 = blockIdx.y * 128;
  const int n0   = blockIdx.x * 128;

  const int sRow = lane >> 2;
  const int sCol = (lane & 3) * 8;
  const long aA0 = (long)(row0 + wave * 32 +      sRow) * HIDDEN + sCol;
  const long aA1 = (long)(row0 + wave * 32 + 16 + sRow) * HIDDEN + sCol;
  const long aB0 = (long)(n0   + wave * 32 +      sRow) * HIDDEN + sCol;
  const long aB1 = (long)(n0   + wave * 32 + 16 + sRow) * HIDDEN + sCol;
  __bf16* lA0 = sA + wave * 1024;
  __bf16* lA1 = sA + wave * 1024 + 512;
  __bf16* lB0 = sB + wave * 1024;
  __bf16* lB1 = sB + wave * 1024 + 512;

  const int kr = (lane >> 4) * 8;
  const int rA = (waveM * 64 + (lane & 15)) * 32 + kr;
  const int rB = (waveN * 64 + (lane & 15)) * 32 + kr;

  f32x4 acc[4][4];
#pragma unroll
  for (int fm = 0; fm < 4; ++fm)
#pragma unroll
    for (int fn = 0; fn < 4; ++fn)
      acc[fm][fn] = (f32x4){0.f, 0.f, 0.f, 0.f};

  for (int k0 = 0; k0 < HIDDEN; k0 += 32) {
    __syncthreads();
    glds16(cnb + aA0 + k0, lA0);
    glds16(cnb + aA1 + k0, lA1);
    glds16(Whb + aB0 + k0, lB0);
    glds16(Whb + aB1 + k0, lB1);
    __syncthreads();

    bf16x8 a[4], b[4];
#pragma unroll
    for (int f = 0; f < 4; ++f) {
      a[f] = *(const bf16x8*)(sA + rA + f * 16 * 32);
      b[f] = *(const bf16x8*)(sB + rB + f * 16 * 32);
    }
#pragma unroll
    for (int fm = 0; fm < 4; ++fm)
#pragma unroll
      for (int fn = 0; fn < 4; ++fn)
        acc[fm][fn] = __builtin_amdgcn_mfma_f32_16x16x32_bf16(a[fm], b[fn], acc[fm][fn], 0, 0, 0);
  }

  const int colB = n0 + waveN * 64 + (lane & 15);
  const int rowB = row0 + waveM * 64 + ((lane >> 4) << 2);
#pragma unroll
  for (int fn = 0; fn < 4; ++fn) {
    const int col = colB + fn * 16;
    const float bv = bh[col];
#pragma unroll
    for (int fm = 0; fm < 4; ++fm) {
#pragma unroll
      for (int rr = 0; rr < 4; ++rr) {
        const int row = rowB + fm * 16 + rr;
        const size_t idx = (size_t)row * HIDDEN + col;
        const float v = tanh_fast(acc[fm][fn][rr] + bv);
        const float ov = out1[idx];  // sigm(o) stashed by gates kernel
        out1[idx] = v * ov;
      }
    }
  }
}

extern "C" void kernel_launch(void* const* d_in, const int* in_sizes, int n_in,
                              void* d_out, int out_size, void* d_ws, size_t ws_size,
                              hipStream_t stream) {
  const float* x   = (const float*)d_in[0];
  const float* st  = (const float*)d_in[1];
  const float* lt  = (const float*)d_in[2];
  const float* Wf  = (const float*)d_in[3];
  const float* bfp = (const float*)d_in[4];
  const float* Wi  = (const float*)d_in[5];
  const float* bip = (const float*)d_in[6];
  const float* Wc  = (const float*)d_in[7];
  const float* bcp = (const float*)d_in[8];
  const float* Wo  = (const float*)d_in[9];
  const float* bop = (const float*)d_in[10];
  const float* Wh  = (const float*)d_in[11];
  const float* bh  = (const float*)d_in[12];

  float* out1 = (float*)d_out;                        // output [B,H] f32
  float* out2 = out1 + (size_t)BATCH * HIDDEN;        // C_new [B,H] f32

  // workspace (bf16): A | W4 | Wh | flt | ig   (~176 MB); cnb reuses A (dead after gates)
  __bf16* Ab  = (__bf16*)d_ws;                        // [BATCH, KD]
  __bf16* W4b = Ab + (size_t)BATCH * KD;              // [4, HIDDEN, KD]
  __bf16* Whb = W4b + (size_t)4 * HIDDEN * KD;        // [HIDDEN, HIDDEN]
  __bf16* Flt = Whb + (size_t)HIDDEN * HIDDEN;        // [BATCH, HIDDEN]
  __bf16* Ig  = Flt + (size_t)BATCH * HIDDEN;         // [BATCH, HIDDEN]
  __bf16* Cnb = Ab;                                   // reuse A region

  cvtA_kernel<<<dim3((BATCH * (long)KD) / 2048), 256, 0, stream>>>(x, st, Ab);
  cvtW_kernel<<<dim3((HIDDEN * (long)KD) / 2048, 4), 256, 0, stream>>>(Wf, Wi, Wc, Wo, W4b);
  cvtC_kernel<<<dim3((HIDDEN * (long)HIDDEN) / 2048), 256, 0, stream>>>(Wh, Whb);

  dim3 grid(HIDDEN / 128, BATCH / 128, 4);  // (16, 64, 4)
  lstm_gates_kernel<<<grid, 256, 0, stream>>>(Ab, W4b, lt, bfp, bip, bcp, bop,
                                              out1, out2, Flt, Ig);
  lstm_cell_kernel<<<dim3((BATCH * (long)HIDDEN) / 2048), 256, 0, stream>>>(Flt, Ig, out2, Cnb);
  dim3 grid2(HIDDEN / 128, BATCH / 128);
  lstm_out_kernel<<<grid2, 256, 0, stream>>>(Cnb, Whb, bh, out1);
}

// Round 3
// 954.974 us; speedup vs baseline: 2.3842x; 1.1007x over previous
//
#include <hip/hip_runtime.h>
#include <hip/hip_bf16.h>

typedef __bf16 bf16x8 __attribute__((ext_vector_type(8)));
typedef float f32x4 __attribute__((ext_vector_type(4)));

static constexpr int BATCH  = 8192;
static constexpr int EMBED  = 1024;
static constexpr int HIDDEN = 2048;
static constexpr int KD     = EMBED + HIDDEN;  // 3072

__device__ __forceinline__ float sigm(float x) { return 1.0f / (1.0f + __expf(-x)); }
__device__ __forceinline__ float tanh_fast(float x) { return 2.0f / (1.0f + __expf(-2.0f * x)) - 1.0f; }

// load 8 f32 -> bf16x8 (one-time convert kernels)
__device__ __forceinline__ bf16x8 loadcvt8(const float* __restrict__ p) {
  f32x4 lo = *(const f32x4*)p;
  f32x4 hi = *(const f32x4*)(p + 4);
  bf16x8 r;
  r[0] = (__bf16)lo[0]; r[1] = (__bf16)lo[1]; r[2] = (__bf16)lo[2]; r[3] = (__bf16)lo[3];
  r[4] = (__bf16)hi[0]; r[5] = (__bf16)hi[1]; r[6] = (__bf16)hi[2]; r[7] = (__bf16)hi[3];
  return r;
}

// async global->LDS, 16B per lane. LDS dest = wave-uniform base + lane*16.
__device__ __forceinline__ void glds16(const void* g, void* l) {
  __builtin_amdgcn_global_load_lds((const __attribute__((address_space(1))) void*)g,
                                   (__attribute__((address_space(3))) void*)l, 16, 0, 0);
}

// ---------------- one-time converts (f32 -> bf16) ----------------
__global__ __launch_bounds__(256) void cvtA_kernel(const float* __restrict__ x,
                                                   const float* __restrict__ st,
                                                   __bf16* __restrict__ dst) {
  const long i8 = ((long)blockIdx.x * 256 + threadIdx.x) * 8;
  const int r = (int)(i8 / KD);
  const int c = (int)(i8 - (long)r * KD);
  const float* s = (c < EMBED) ? (x + (long)r * EMBED + c)
                               : (st + (long)r * HIDDEN + (c - EMBED));
  *(bf16x8*)(dst + i8) = loadcvt8(s);
}

__global__ __launch_bounds__(256) void cvtW_kernel(const float* __restrict__ Wf,
                                                   const float* __restrict__ Wi,
                                                   const float* __restrict__ Wc,
                                                   const float* __restrict__ Wo,
                                                   __bf16* __restrict__ dst) {
  const int g = blockIdx.y;
  const float* s = (g == 0) ? Wf : (g == 1) ? Wi : (g == 2) ? Wc : Wo;
  const long off = ((long)blockIdx.x * 256 + threadIdx.x) * 8;
  *(bf16x8*)(dst + (long)g * HIDDEN * KD + off) = loadcvt8(s + off);
}

__global__ __launch_bounds__(256) void cvtC_kernel(const float* __restrict__ s,
                                                   __bf16* __restrict__ d) {
  const long off = ((long)blockIdx.x * 256 + threadIdx.x) * 8;
  *(bf16x8*)(d + off) = loadcvt8(s + off);
}

// ============ 256x256 pipelined GEMM core, BK=32, ring-4 LDS, 8 waves ============
// acc[8][4]: wave (2M x 4N) owns 128x64; C/D: col=lane&15, row=(lane>>4)*4+reg.
// LDS swizzle (T2): byte col ^= ((row>>2)&3)<<4 within 64B rows; applied on the
// pre-swizzled per-lane GLOBAL source (linear glds dest, rule #21) and on reads.
template<int LDA, int LDB, int NT>
__device__ __forceinline__ void gemm256(const __bf16* __restrict__ Agl,  // + row0*LDA
                                        const __bf16* __restrict__ Bgl,  // + col0*LDB
                                        f32x4 (&acc)[8][4])
{
  __shared__ __align__(16) __bf16 lds[4][2][256 * 32];  // [buf][A,B][256 rows x 32 k]

  const int tid  = threadIdx.x;
  const int lane = tid & 63;
  const int w    = tid >> 6;     // 0..7

  // staging: chunk = 16 rows x 32 cols (1KB per wave-glds). lane -> row l>>2,
  // source col pre-swizzled: ((l&3)^(l>>4))*8 elements.
  const int sRow = lane >> 2;
  const int sCol = (((lane & 3) ^ (lane >> 4)) << 3);
  const __bf16* gA = Agl + (size_t)(w * 16 + sRow) * LDA + sCol;
  const __bf16* gB = Bgl + (size_t)(w * 16 + sRow) * LDB + sCol;
  const int ldsLo = w * 512;          // element offset of wave's chunk (rows w*16)
  const int ldsHi = (w + 8) * 512;    // rows 128 + w*16

  // fragment reads: A[m][k]: m=lane&15, k=(lane>>4)*8+j; swizzled col (2-way = free)
  const int rm    = lane & 15;
  const int rdCol = (((lane >> 4) ^ ((lane >> 2) & 3)) << 3);
  const int aOff  = ((w >> 2) * 128 + rm) * 32 + rdCol;   // + fm*512
  const int bOff  = ((w & 3) * 64 + rm) * 32 + rdCol;     // + fn*512

  auto stage = [&](int b, int jt) {
    const size_t ko = (size_t)jt * 32;
    glds16(gA + ko,                     &lds[b][0][ldsLo]);
    glds16(gA + ko + (size_t)128 * LDA, &lds[b][0][ldsHi]);
    glds16(gB + ko,                     &lds[b][1][ldsLo]);
    glds16(gB + ko + (size_t)128 * LDB, &lds[b][1][ldsHi]);
  };

  // counted fence (T4): tiles jt+2, jt+3 (8 glds) stay in flight; tile jt+1 forced done.
  auto fence = [&]() {
    __builtin_amdgcn_sched_barrier(0);
    asm volatile("s_waitcnt vmcnt(8)" ::: "memory");
    __builtin_amdgcn_sched_barrier(0);
    __builtin_amdgcn_s_barrier();
    __builtin_amdgcn_sched_barrier(0);
  };

  stage(0, 0); stage(1, 1); stage(2, 2);   // prologue: depth-3
  fence();                                  // tile 0 ready (8 newer may fly)

  auto step = [&](int b, int jt) {
    if (jt + 3 < NT) stage((b + 3) & 3, jt + 3);   // buf (b+3)&3 last read at jt-1
    bf16x8 aF[8], bF[4];
#pragma unroll
    for (int fm = 0; fm < 8; ++fm)
      aF[fm] = *(const bf16x8*)&lds[b][0][aOff + fm * 512];
#pragma unroll
    for (int fn = 0; fn < 4; ++fn)
      bF[fn] = *(const bf16x8*)&lds[b][1][bOff + fn * 512];
    __builtin_amdgcn_s_setprio(1);
#pragma unroll
    for (int fm = 0; fm < 8; ++fm)
#pragma unroll
      for (int fn = 0; fn < 4; ++fn)
        acc[fm][fn] = __builtin_amdgcn_mfma_f32_16x16x32_bf16(aF[fm], bF[fn], acc[fm][fn], 0, 0, 0);
    __builtin_amdgcn_s_setprio(0);
    fence();
  };

  for (int jt = 0; jt < NT; jt += 4) {     // NT % 4 == 0 (96, 64)
    step(0, jt); step(1, jt + 1); step(2, jt + 2); step(3, jt + 3);
  }
}

// ---------------- Kernel 1: fused 4-gate GEMM (N=8192 fused) ----------------
// grid (32, 32) x 512 thr. gate = bx>>3 (256 | 2048 -> block-uniform).
__global__ __launch_bounds__(512, 2) void lstm_gates_kernel(
    const __bf16* __restrict__ A,   // [BATCH, KD]
    const __bf16* __restrict__ W4,  // [4*HIDDEN, KD] fused rows
    const float* __restrict__ lt,
    const float* __restrict__ bfp, const float* __restrict__ bip,
    const float* __restrict__ bcp, const float* __restrict__ bop,
    float* __restrict__ out1, float* __restrict__ out2,
    __bf16* __restrict__ flt, __bf16* __restrict__ ig)
{
  // T1 XCD swizzle (nwg = 1024, % 8 == 0)
  int lin = blockIdx.y * 32 + blockIdx.x;
  lin = (lin & 7) * 128 + (lin >> 3);
  const int bx = lin & 31;
  const int by = lin >> 5;

  const int row0 = by * 256;
  const int n0f  = bx * 256;   // fused hidden col base

  f32x4 acc[8][4];
#pragma unroll
  for (int fm = 0; fm < 8; ++fm)
#pragma unroll
    for (int fn = 0; fn < 4; ++fn)
      acc[fm][fn] = (f32x4){0.f, 0.f, 0.f, 0.f};

  gemm256<KD, KD, KD / 32>(A + (size_t)row0 * KD, W4 + (size_t)n0f * KD, acc);

  const int tid  = threadIdx.x;
  const int lane = tid & 63;
  const int w    = tid >> 6;
  const int gate = n0f >> 11;
  const int colB = (n0f & 2047) + (w & 3) * 64 + (lane & 15);
  const int rowB = row0 + (w >> 2) * 128 + ((lane >> 4) << 2);
  const float* bias = (gate == 0) ? bfp : (gate == 1) ? bip : (gate == 2) ? bcp : bop;

#pragma unroll
  for (int fn = 0; fn < 4; ++fn) {
    const int col = colB + fn * 16;
    const float bv = bias[col];
#pragma unroll
    for (int fm = 0; fm < 8; ++fm) {
#pragma unroll
      for (int rr = 0; rr < 4; ++rr) {
        const int row = rowB + fm * 16 + rr;
        const size_t idx = (size_t)row * HIDDEN + col;
        const float v = acc[fm][fn][rr] + bv;
        if (gate == 0) {
          flt[idx] = (__bf16)(sigm(v) * lt[idx]);
        } else if (gate == 1) {
          ig[idx] = (__bf16)sigm(v);
        } else if (gate == 2) {
          out2[idx] = tanh_fast(v);   // tanh(c~) temp
        } else {
          out1[idx] = sigm(v);        // o temp
        }
      }
    }
  }
}

// ---------------- elementwise: C_new = flt + ig*tc ----------------
__global__ __launch_bounds__(256) void lstm_cell_kernel(
    const __bf16* __restrict__ flt, const __bf16* __restrict__ ig,
    float* __restrict__ out2 /* in: tanh(c), out: C_new */,
    __bf16* __restrict__ cnb)
{
  const long i8 = ((long)blockIdx.x * 256 + threadIdx.x) * 8;
  bf16x8 f8 = *(const bf16x8*)(flt + i8);
  bf16x8 i8v = *(const bf16x8*)(ig + i8);
  f32x4 t0 = *(const f32x4*)(out2 + i8);
  f32x4 t1 = *(const f32x4*)(out2 + i8 + 4);
  f32x4 c0, c1;
  bf16x8 cb;
#pragma unroll
  for (int j = 0; j < 4; ++j) {
    c0[j] = (float)f8[j] + (float)i8v[j] * t0[j];
    c1[j] = (float)f8[j + 4] + (float)i8v[j + 4] * t1[j];
    cb[j] = (__bf16)c0[j];
    cb[j + 4] = (__bf16)c1[j];
  }
  *(f32x4*)(out2 + i8) = c0;
  *(f32x4*)(out2 + i8 + 4) = c1;
  *(bf16x8*)(cnb + i8) = cb;
}

// ---------------- Kernel 2: output = tanh(C_new @ W_h2o^T + b) * o ----------------
// grid (8, 32) x 512 thr.
__global__ __launch_bounds__(512, 2) void lstm_out_kernel(
    const __bf16* __restrict__ cnb, const __bf16* __restrict__ Whb,
    const float* __restrict__ bh, float* __restrict__ out1)
{
  int lin = blockIdx.y * 8 + blockIdx.x;   // nwg = 256
  lin = (lin & 7) * 32 + (lin >> 3);
  const int bx = lin & 7;
  const int by = lin >> 3;

  const int row0 = by * 256;
  const int n0   = bx * 256;

  f32x4 acc[8][4];
#pragma unroll
  for (int fm = 0; fm < 8; ++fm)
#pragma unroll
    for (int fn = 0; fn < 4; ++fn)
      acc[fm][fn] = (f32x4){0.f, 0.f, 0.f, 0.f};

  gemm256<HIDDEN, HIDDEN, HIDDEN / 32>(cnb + (size_t)row0 * HIDDEN,
                                       Whb + (size_t)n0 * HIDDEN, acc);

  const int tid  = threadIdx.x;
  const int lane = tid & 63;
  const int w    = tid >> 6;
  const int colB = n0 + (w & 3) * 64 + (lane & 15);
  const int rowB = row0 + (w >> 2) * 128 + ((lane >> 4) << 2);

#pragma unroll
  for (int fn = 0; fn < 4; ++fn) {
    const int col = colB + fn * 16;
    const float bv = bh[col];
#pragma unroll
    for (int fm = 0; fm < 8; ++fm) {
#pragma unroll
      for (int rr = 0; rr < 4; ++rr) {
        const int row = rowB + fm * 16 + rr;
        const size_t idx = (size_t)row * HIDDEN + col;
        const float v = tanh_fast(acc[fm][fn][rr] + bv);
        const float ov = out1[idx];  // sigm(o) stashed by gates kernel
        out1[idx] = v * ov;
      }
    }
  }
}

extern "C" void kernel_launch(void* const* d_in, const int* in_sizes, int n_in,
                              void* d_out, int out_size, void* d_ws, size_t ws_size,
                              hipStream_t stream) {
  const float* x   = (const float*)d_in[0];
  const float* st  = (const float*)d_in[1];
  const float* lt  = (const float*)d_in[2];
  const float* Wf  = (const float*)d_in[3];
  const float* bfp = (const float*)d_in[4];
  const float* Wi  = (const float*)d_in[5];
  const float* bip = (const float*)d_in[6];
  const float* Wc  = (const float*)d_in[7];
  const float* bcp = (const float*)d_in[8];
  const float* Wo  = (const float*)d_in[9];
  const float* bop = (const float*)d_in[10];
  const float* Wh  = (const float*)d_in[11];
  const float* bh  = (const float*)d_in[12];

  float* out1 = (float*)d_out;                        // output [B,H] f32
  float* out2 = out1 + (size_t)BATCH * HIDDEN;        // C_new [B,H] f32

  // workspace (bf16): A | W4 | Wh | flt | ig ; cnb reuses A (dead after gates)
  __bf16* Ab  = (__bf16*)d_ws;                        // [BATCH, KD]
  __bf16* W4b = Ab + (size_t)BATCH * KD;              // [4, HIDDEN, KD]
  __bf16* Whb = W4b + (size_t)4 * HIDDEN * KD;        // [HIDDEN, HIDDEN]
  __bf16* Flt = Whb + (size_t)HIDDEN * HIDDEN;        // [BATCH, HIDDEN]
  __bf16* Ig  = Flt + (size_t)BATCH * HIDDEN;         // [BATCH, HIDDEN]
  __bf16* Cnb = Ab;                                   // reuse A region

  cvtA_kernel<<<dim3((BATCH * (long)KD) / 2048), 256, 0, stream>>>(x, st, Ab);
  cvtW_kernel<<<dim3((HIDDEN * (long)KD) / 2048, 4), 256, 0, stream>>>(Wf, Wi, Wc, Wo, W4b);
  cvtC_kernel<<<dim3((HIDDEN * (long)HIDDEN) / 2048), 256, 0, stream>>>(Wh, Whb);

  dim3 grid1(8192 / 256, BATCH / 256);  // (32, 32) fused-N gates
  lstm_gates_kernel<<<grid1, 512, 0, stream>>>(Ab, W4b, lt, bfp, bip, bcp, bop,
                                               out1, out2, Flt, Ig);
  lstm_cell_kernel<<<dim3((BATCH * (long)HIDDEN) / 2048), 256, 0, stream>>>(Flt, Ig, out2, Cnb);
  dim3 grid2(HIDDEN / 256, BATCH / 256);  // (8, 32)
  lstm_out_kernel<<<grid2, 512, 0, stream>>>(Cnb, Whb, bh, out1);
}